// Round 10
// baseline (266.128 us; speedup 1.0000x reference)
//
#include <hip/hip_runtime.h>

typedef unsigned short u16;
typedef unsigned int u32;
typedef __attribute__((ext_vector_type(4))) int v4i;
typedef __attribute__((ext_vector_type(4))) float f32x4;
typedef __attribute__((ext_vector_type(16))) float f32x16;
typedef __attribute__((ext_vector_type(4))) u16 v4u;
typedef __attribute__((ext_vector_type(2))) u32 u32x2;
typedef __attribute__((ext_vector_type(8))) __bf16 bf16x8;

#define B_ 4
#define T_ 2048
#define C_ 1024
#define H_ 16
#define HD_ 64
#define C3_ 3072

__device__ __forceinline__ u16 f2b(float f) {
    unsigned u = __builtin_bit_cast(unsigned, f);
    u += 0x7FFFu + ((u >> 16) & 1u);
    return (u16)(u >> 16);
}
__device__ __forceinline__ float b2f(u16 h) {
    unsigned u = ((unsigned)h) << 16;
    return __builtin_bit_cast(float, u);
}
__device__ __forceinline__ u32 pk2(float lo, float hi) {
    __bf16 a = (__bf16)lo, b = (__bf16)hi;
    return (u32)__builtin_bit_cast(u16, a) | ((u32)__builtin_bit_cast(u16, b) << 16);
}
// async global->LDS, 16B per lane; LDS dest = uniform base + lane*16
__device__ __forceinline__ void glds16(const u16* g, u16* l) {
    __builtin_amdgcn_global_load_lds((const __attribute__((address_space(1))) void*)g,
                                     (__attribute__((address_space(3))) void*)l, 16, 0, 0);
}

// ---------------- cast f32 -> bf16 ----------------
__global__ __launch_bounds__(256) void cast_f32_bf16(const float* __restrict__ in,
                                                     u16* __restrict__ out, int n4) {
    int i = blockIdx.x * 256 + threadIdx.x;
    if (i >= n4) return;
    f32x4 v = *(const f32x4*)(in + (size_t)i * 4);
    v4u o;
    o[0] = f2b(v[0]); o[1] = f2b(v[1]); o[2] = f2b(v[2]); o[3] = f2b(v[3]);
    *(v4u*)(out + (size_t)i * 4) = o;
}

// ---------------- rope table ----------------
__global__ __launch_bounds__(256) void rope_tab(u16* __restrict__ rope) {
    int id = blockIdx.x * 256 + threadIdx.x;   // T_*32 entries
    int t = id >> 5, j = id & 31;
    float invf = exp2f(-(float)j * (13.287712379549449f / 32.0f));  // 10000^(-j/32)
    float fr = (float)t * invf;
    float s, c;
    sincosf(fr, &s, &c);
    rope[id * 2]     = f2b(c);
    rope[id * 2 + 1] = f2b(s);
}

// ---------------- GEMM v5: BK=64 glds + XOR swizzle + bijective XCD remap ----
__device__ __forceinline__ void store_out(u16* p, float v)   { *p = f2b(v); }
__device__ __forceinline__ void store_out(float* p, float v) { *p = v; }

template <typename OutT>
__global__ __launch_bounds__(256) void gemm_bt5(const u16* __restrict__ A, const u16* __restrict__ Bm,
                                                OutT* __restrict__ Cout, int Mdim, int Ndim, int Kdim) {
    __shared__ u16 As[8192];     // [128][64] swizzled, 16 KB
    __shared__ u16 Bs[8192];
    const int tid = threadIdx.x;
    // T1: bijective XCD remap (nwg % 8 == 0 for all our launches)
    const int F = blockIdx.y * gridDim.x + blockIdx.x;
    const int cpx = (gridDim.x * gridDim.y) >> 3;
    const int wg = (F & 7) * cpx + (F >> 3);
    const int row0 = (wg / gridDim.x) * 128;
    const int col0 = (wg % gridDim.x) * 128;
    const int w = tid >> 6, lane = tid & 63;
    const int wm = w >> 1, wn = w & 1;
    const int lr = lane & 15, lk = lane >> 4;

    const f32x4 zf = {0.f, 0.f, 0.f, 0.f};
    f32x4 acc[4][4];
#pragma unroll
    for (int m = 0; m < 4; m++)
#pragma unroll
        for (int n = 0; n < 4; n++) acc[m][n] = zf;

    const u16* Ab = A + (size_t)row0 * Kdim;
    const u16* Bb = Bm + (size_t)col0 * Kdim;
    const int srw = lane >> 3;                       // 0..7 within inst
    const int gch = (lane & 7) ^ (srw & 7);          // inverse swizzle on global source
    const size_t grow[4] = {
        (size_t)(w * 32 + 0 * 8 + srw) * Kdim + gch * 8,
        (size_t)(w * 32 + 1 * 8 + srw) * Kdim + gch * 8,
        (size_t)(w * 32 + 2 * 8 + srw) * Kdim + gch * 8,
        (size_t)(w * 32 + 3 * 8 + srw) * Kdim + gch * 8 };
    const int rx = lr & 7;

    for (int k0 = 0; k0 < Kdim; k0 += 64) {
#pragma unroll
        for (int j = 0; j < 4; j++) glds16(Ab + grow[j] + k0, As + (w * 32 + j * 8) * 64);
#pragma unroll
        for (int j = 0; j < 4; j++) glds16(Bb + grow[j] + k0, Bs + (w * 32 + j * 8) * 64);
        __syncthreads();
#pragma unroll
        for (int kk = 0; kk < 2; kk++) {
            const int chx = ((kk * 4 + lk) ^ rx) * 8;
            bf16x8 af[4], bfr[4];
#pragma unroll
            for (int m = 0; m < 4; m++) af[m]  = *(const bf16x8*)&As[(wm * 64 + m * 16 + lr) * 64 + chx];
#pragma unroll
            for (int n = 0; n < 4; n++) bfr[n] = *(const bf16x8*)&Bs[(wn * 64 + n * 16 + lr) * 64 + chx];
#pragma unroll
            for (int m = 0; m < 4; m++)
#pragma unroll
                for (int n = 0; n < 4; n++)
                    acc[m][n] = __builtin_amdgcn_mfma_f32_16x16x32_bf16(af[m], bfr[n], acc[m][n], 0, 0, 0);
        }
        __syncthreads();
    }
#pragma unroll
    for (int m = 0; m < 4; m++)
#pragma unroll
        for (int n = 0; n < 4; n++) {
            const int rr = row0 + wm * 64 + m * 16 + lk * 4;
            const int cc = col0 + wn * 64 + n * 16 + lr;
#pragma unroll
            for (int j = 0; j < 4; j++)
                store_out(Cout + (size_t)(rr + j) * Ndim + cc, acc[m][n][j]);
        }
}

// ---------------- RMSNorm + RoPE for q,k; transpose v -> [bh][d][t] ----------
__global__ __launch_bounds__(256) void norm_rope(const u16* __restrict__ qkv, u16* __restrict__ Qn,
                                                 u16* __restrict__ Kn, u16* __restrict__ Vt,
                                                 const u16* __restrict__ rope) {
    __shared__ u16 sl[3][64][72];
    const int tid = threadIdx.x, bid = blockIdx.x;
    const int tt = bid & 31, bh = bid >> 5;
    const int b = bh >> 4, h = bh & 15;
    const int t0 = tt * 64;
    const size_t base = ((size_t)(b * T_) + t0) * C3_ + h * HD_;
#pragma unroll
    for (int i = 0; i < 6; i++) {
        int c = tid + i * 256;            // 1536 16B chunks
        int p = c >> 9, rc = c & 511;
        int r = rc >> 3, ch = rc & 7;
        *(v4i*)&sl[p][r][ch * 8] = *(const v4i*)(qkv + base + (size_t)r * C3_ + p * C_ + ch * 8);
    }
    __syncthreads();
    const int row = tid >> 2, q4 = tid & 3;  // 4 lanes per row
    const u16* rp = rope + (size_t)(t0 + row) * 64;
#pragma unroll
    for (int p = 0; p < 2; p++) {            // p=0: q, p=1: k
        float ss = 0.f;
#pragma unroll
        for (int j = 0; j < 16; j++) { float v = b2f(sl[p][row][q4 * 16 + j]); ss += v * v; }
        ss += __shfl_xor(ss, 1, 64);
        ss += __shfl_xor(ss, 2, 64);
        const float rms = rsqrtf(ss * (1.f / 64.f) + 1.1920929e-7f);
        u16* outp = (p == 0 ? Qn : Kn) + ((size_t)bh * T_ + t0 + row) * HD_;
#pragma unroll
        for (int j = 0; j < 16; j++) {
            int d = q4 * 16 + j;
            float y;
            if (d < 32) {
                float x1 = b2f(sl[p][row][d]) * rms;
                float x2 = b2f(sl[p][row][d + 32]) * rms;
                y = x1 * b2f(rp[d * 2]) + x2 * b2f(rp[d * 2 + 1]);      // x1*cos + x2*sin
            } else {
                int dd = d - 32;
                float x1 = b2f(sl[p][row][dd]) * rms;
                float x2 = b2f(sl[p][row][d]) * rms;
                y = x2 * b2f(rp[dd * 2]) - x1 * b2f(rp[dd * 2 + 1]);    // x2*cos - x1*sin
            }
            outp[d] = f2b(y);
        }
    }
    const int d = tid >> 2, tq = tid & 3;
    u16* vout = Vt + ((size_t)bh * HD_ + d) * T_ + t0 + tq * 16;
#pragma unroll
    for (int jj = 0; jj < 4; jj++) {
        v4u pk;
#pragma unroll
        for (int j2 = 0; j2 < 4; j2++) pk[j2] = sl[2][tq * 16 + jj * 4 + j2][d];
        *(v4u*)(vout + jj * 4) = pk;
    }
}

// ---------------- causal flash attention v7: + T14 async-stage split ---------
__global__ __launch_bounds__(256, 4) void attn_fwd7(const u16* __restrict__ Qn, const u16* __restrict__ Kn,
                                                    const u16* __restrict__ Vt, u16* __restrict__ Yb) {
    __shared__ u16 Ks[64 * 64];
    __shared__ u16 Vs[64 * 64];
    const int tid = threadIdx.x;
    const int w = tid >> 6, lane = tid & 63, la = lane & 31, hi = lane >> 5;
    const int gid = blockIdx.x;
    const int bh = gid & 63, qb = 15 - (gid >> 6);
    const int b = bh >> 4, h = bh & 15;
    const int q0w = qb * 128 + w * 32;
    const int q = q0w + la;
    const u16* Qp = Qn + (size_t)bh * T_ * HD_;
    const u16* Kp = Kn + (size_t)bh * T_ * HD_;
    const u16* Vp = Vt + (size_t)bh * HD_ * T_;
    const float SC = 0.125f * 1.44269504088896341f;   // scale * log2(e)

    bf16x8 qf[4];
#pragma unroll
    for (int c = 0; c < 4; c++)
        qf[c] = *(const bf16x8*)(Qp + (size_t)q * HD_ + c * 16 + hi * 8);

    v4i oi; oi[0] = oi[1] = oi[2] = oi[3] = 0x3F803F80;        // bf16 1.0 x8
    const bf16x8 onesf = __builtin_bit_cast(bf16x8, oi);

    f32x16 O0, O1, lsum;
#pragma unroll
    for (int r = 0; r < 16; r++) { O0[r] = 0.f; O1[r] = 0.f; lsum[r] = 0.f; }
    float m = -3e38f;
    const int lastt = q0w >> 6;
    const int ntile = 2 * qb + 2;
    const int srow0 = tid >> 3, scol = (tid & 7) * 8;            // u16 units
    const int srow1 = srow0 + 32;
    const int sw0 = srow0 * 64 + (scol ^ ((srow0 & 7) << 3));
    const int sw1 = srow1 * 64 + (scol ^ ((srow1 & 7) << 3));
    const int swl = (la & 7) << 3;                               // frag-read XOR
    // T14: per-tile global sources; tile-0 loads issued before the loop
    const u16* Kg0 = Kp + (size_t)srow0 * HD_ + scol;
    const u16* Kg1 = Kp + (size_t)srow1 * HD_ + scol;
    const u16* Vg0 = Vp + (size_t)srow0 * T_ + scol;
    const u16* Vg1 = Vp + (size_t)srow1 * T_ + scol;
    v4i rk0 = *(const v4i*)Kg0;
    v4i rk1 = *(const v4i*)Kg1;
    v4i rv0 = *(const v4i*)Vg0;
    v4i rv1 = *(const v4i*)Vg1;

    for (int kt = 0; kt < ntile; kt++) {
        const int kv0 = kt * 64;
        __syncthreads();                     // prev tile's LDS readers done
        *(v4i*)&Ks[sw0] = rk0;
        *(v4i*)&Ks[sw1] = rk1;
        *(v4i*)&Vs[sw0] = rv0;
        *(v4i*)&Vs[sw1] = rv1;
        __syncthreads();                     // LDS published
        if (kt + 1 < ntile) {                // prefetch next tile (in flight during compute)
            rk0 = *(const v4i*)(Kg0 + (size_t)(kv0 + 64) * HD_);
            rk1 = *(const v4i*)(Kg1 + (size_t)(kv0 + 64) * HD_);
            rv0 = *(const v4i*)(Vg0 + kv0 + 64);
            rv1 = *(const v4i*)(Vg1 + kv0 + 64);
        }
        if (kv0 > q0w + 31) continue;        // past diagonal; barriers stay matched
        f32x16 s0, s1;
#pragma unroll
        for (int r = 0; r < 16; r++) { s0[r] = 0.f; s1[r] = 0.f; }
#pragma unroll
        for (int c = 0; c < 4; c++) {
            const int cb = c * 16 + hi * 8;
            bf16x8 kfa = *(const bf16x8*)&Ks[la * 64 + (cb ^ swl)];
            bf16x8 kfb = *(const bf16x8*)&Ks[(32 + la) * 64 + (cb ^ swl)];
            s0 = __builtin_amdgcn_mfma_f32_32x32x16_bf16(kfa, qf[c], s0, 0, 0, 0);
            s1 = __builtin_amdgcn_mfma_f32_32x32x16_bf16(kfb, qf[c], s1, 0, 0, 0);
        }
        if (kt == lastt) {
#pragma unroll
            for (int r = 0; r < 16; r++) {
                const int cr = (r & 3) + 8 * (r >> 2) + 4 * hi;
                if (kv0 + cr > q)      s0[r] = -3e38f;
                if (kv0 + 32 + cr > q) s1[r] = -3e38f;
            }
        }
        float mx = fmaxf(s0[0], s1[0]);
#pragma unroll
        for (int r = 1; r < 16; r++) mx = fmaxf(mx, fmaxf(s0[r], s1[r]));
        {   // cross-half max via permlane32_swap (VALU)
            int mi = __builtin_bit_cast(int, mx);
            auto sw = __builtin_amdgcn_permlane32_swap(mi, mi, false, false);
            mx = fmaxf(__builtin_bit_cast(float, sw[0]), __builtin_bit_cast(float, sw[1]));
        }
        if (__ballot(mx > m + 16.6355324f)) {   // T13 defer-max (3.0/SC)
            const float mn = fmaxf(m, mx);
            const float al = exp2f((m - mn) * SC);
            m = mn;
            lsum[0] *= al;                      // only row 0 of lsum is consumed
            O0 *= al;
            O1 *= al;
        }
        const float nm = -m * SC;
        float p0[16], p1[16];
#pragma unroll
        for (int r = 0; r < 16; r++) {
            p0[r] = exp2f(fmaf(s0[r], SC, nm));
            p1[r] = exp2f(fmaf(s1[r], SC, nm));
        }
#pragma unroll
        for (int g = 0; g < 2; g++) {
            u32 P2[8];
#pragma unroll
            for (int j = 0; j < 8; j++)
                P2[j] = g ? pk2(p1[2 * j], p1[2 * j + 1]) : pk2(p0[2 * j], p0[2 * j + 1]);
            auto s02 = __builtin_amdgcn_permlane32_swap((int)P2[0], (int)P2[2], false, false);
            auto s13 = __builtin_amdgcn_permlane32_swap((int)P2[1], (int)P2[3], false, false);
            auto s46 = __builtin_amdgcn_permlane32_swap((int)P2[4], (int)P2[6], false, false);
            auto s57 = __builtin_amdgcn_permlane32_swap((int)P2[5], (int)P2[7], false, false);
            v4i w0, w1;
            w0[0] = s02[0]; w0[1] = s13[0]; w0[2] = s02[1]; w0[3] = s13[1];
            w1[0] = s46[0]; w1[1] = s57[0]; w1[2] = s46[1]; w1[3] = s57[1];
            const bf16x8 pa0 = __builtin_bit_cast(bf16x8, w0);
            const bf16x8 pa1 = __builtin_bit_cast(bf16x8, w1);
            lsum = __builtin_amdgcn_mfma_f32_32x32x16_bf16(onesf, pa0, lsum, 0, 0, 0);
            lsum = __builtin_amdgcn_mfma_f32_32x32x16_bf16(onesf, pa1, lsum, 0, 0, 0);
#pragma unroll
            for (int ks = 0; ks < 2; ks++) {
                const bf16x8 pa = ks ? pa1 : pa0;
                const int cb = g * 32 + ks * 16 + hi * 8;
                bf16x8 vfa = *(const bf16x8*)&Vs[la * 64 + (cb ^ swl)];
                bf16x8 vfb = *(const bf16x8*)&Vs[(32 + la) * 64 + (cb ^ swl)];
                O0 = __builtin_amdgcn_mfma_f32_32x32x16_bf16(vfa, pa, O0, 0, 0, 0);
                O1 = __builtin_amdgcn_mfma_f32_32x32x16_bf16(vfb, pa, O1, 0, 0, 0);
            }
        }
    }
    const float inv = 1.f / lsum[0];
    u16* yrow = Yb + ((size_t)(b * T_) + q) * C_ + h * HD_;
#pragma unroll
    for (int r4 = 0; r4 < 4; r4++) {
        u32x2 st0, st1;
        st0[0] = pk2(O0[r4 * 4 + 0] * inv, O0[r4 * 4 + 1] * inv);
        st0[1] = pk2(O0[r4 * 4 + 2] * inv, O0[r4 * 4 + 3] * inv);
        st1[0] = pk2(O1[r4 * 4 + 0] * inv, O1[r4 * 4 + 1] * inv);
        st1[1] = pk2(O1[r4 * 4 + 2] * inv, O1[r4 * 4 + 3] * inv);
        *(u32x2*)(yrow + r4 * 8 + hi * 4)      = st0;
        *(u32x2*)(yrow + 32 + r4 * 8 + hi * 4) = st1;
    }
}

extern "C" void kernel_launch(void* const* d_in, const int* in_sizes, int n_in,
                              void* d_out, int out_size, void* d_ws, size_t ws_size,
                              hipStream_t stream) {
    const float* x      = (const float*)d_in[0];
    const float* w_attn = (const float*)d_in[1];
    const float* w_proj = (const float*)d_in[2];
    float* out = (float*)d_out;
    char* ws = (char*)d_ws;
    // lifetime-overlapped workspace, peak ~104.3 MB
    u16* Wpb = (u16*)(ws + 0);              // 2 MB,   live: all
    u16* Rp  = (u16*)(ws + 2097152);        // 256 KB, live: -> norm
    u16* Xb  = (u16*)(ws + 2359296);        // 16 MB,  live: -> gemm1
    u16* Wab = (u16*)(ws + 19136512);       // 6 MB,   live: -> gemm1
    u16* QKV = (u16*)(ws + 25427968);       // 48 MB,  live: gemm1 -> norm
    u16* Qn  = (u16*)(ws + 2359296);        // 16 MB,  over Xb (dead), norm -> attn
    u16* Kn  = (u16*)(ws + 75759616);       // 16 MB,  norm -> attn
    u16* Vt  = (u16*)(ws + 92536832);       // 16 MB,  norm -> attn  [bh][d][t]
    u16* Yb  = (u16*)(ws + 25427968);       // 16 MB,  over QKV (dead), attn -> gemm2

    cast_f32_bf16<<<8192, 256, 0, stream>>>(x, Xb, 2097152);
    cast_f32_bf16<<<3072, 256, 0, stream>>>(w_attn, Wab, 786432);
    cast_f32_bf16<<<1024, 256, 0, stream>>>(w_proj, Wpb, 262144);
    rope_tab<<<256, 256, 0, stream>>>(Rp);
    gemm_bt5<u16><<<dim3(24, 64), 256, 0, stream>>>(Xb, Wab, QKV, 8192, 3072, 1024);
    norm_rope<<<2048, 256, 0, stream>>>(QKV, Qn, Kn, Vt, Rp);
    attn_fwd7<<<1024, 256, 0, stream>>>(Qn, Kn, Vt, Yb);
    gemm_bt5<float><<<dim3(8, 64), 256, 0, stream>>>(Yb, Wpb, out, 8192, 1024, 1024);
}

// Round 11
// 239.783 us; speedup vs baseline: 1.1099x; 1.1099x over previous
//
#include <hip/hip_runtime.h>

typedef unsigned short u16;
typedef unsigned int u32;
typedef __attribute__((ext_vector_type(4))) int v4i;
typedef __attribute__((ext_vector_type(4))) float f32x4;
typedef __attribute__((ext_vector_type(16))) float f32x16;
typedef __attribute__((ext_vector_type(4))) u16 v4u;
typedef __attribute__((ext_vector_type(2))) u32 u32x2;
typedef __attribute__((ext_vector_type(8))) __bf16 bf16x8;

#define B_ 4
#define T_ 2048
#define C_ 1024
#define H_ 16
#define HD_ 64
#define C3_ 3072

__device__ __forceinline__ u16 f2b(float f) {
    unsigned u = __builtin_bit_cast(unsigned, f);
    u += 0x7FFFu + ((u >> 16) & 1u);
    return (u16)(u >> 16);
}
__device__ __forceinline__ float b2f(u16 h) {
    unsigned u = ((unsigned)h) << 16;
    return __builtin_bit_cast(float, u);
}
__device__ __forceinline__ u32 pk2(float lo, float hi) {
    __bf16 a = (__bf16)lo, b = (__bf16)hi;
    return (u32)__builtin_bit_cast(u16, a) | ((u32)__builtin_bit_cast(u16, b) << 16);
}
// async global->LDS, 16B per lane; LDS dest = uniform base + lane*16
__device__ __forceinline__ void glds16(const u16* g, u16* l) {
    __builtin_amdgcn_global_load_lds((const __attribute__((address_space(1))) void*)g,
                                     (__attribute__((address_space(3))) void*)l, 16, 0, 0);
}

// ---------------- cast f32 -> bf16 ----------------
__global__ __launch_bounds__(256) void cast_f32_bf16(const float* __restrict__ in,
                                                     u16* __restrict__ out, int n4) {
    int i = blockIdx.x * 256 + threadIdx.x;
    if (i >= n4) return;
    f32x4 v = *(const f32x4*)(in + (size_t)i * 4);
    v4u o;
    o[0] = f2b(v[0]); o[1] = f2b(v[1]); o[2] = f2b(v[2]); o[3] = f2b(v[3]);
    *(v4u*)(out + (size_t)i * 4) = o;
}

// ---------------- rope table ----------------
__global__ __launch_bounds__(256) void rope_tab(u16* __restrict__ rope) {
    int id = blockIdx.x * 256 + threadIdx.x;   // T_*32 entries
    int t = id >> 5, j = id & 31;
    float invf = exp2f(-(float)j * (13.287712379549449f / 32.0f));  // 10000^(-j/32)
    float fr = (float)t * invf;
    float s, c;
    sincosf(fr, &s, &c);
    rope[id * 2]     = f2b(c);
    rope[id * 2 + 1] = f2b(s);
}

// ---------------- GEMM v5: BK=64 glds + XOR swizzle + bijective XCD remap ----
__device__ __forceinline__ void store_out(u16* p, float v)   { *p = f2b(v); }
__device__ __forceinline__ void store_out(float* p, float v) { *p = v; }

template <typename OutT>
__global__ __launch_bounds__(256) void gemm_bt5(const u16* __restrict__ A, const u16* __restrict__ Bm,
                                                OutT* __restrict__ Cout, int Mdim, int Ndim, int Kdim) {
    __shared__ u16 As[8192];     // [128][64] swizzled, 16 KB
    __shared__ u16 Bs[8192];
    const int tid = threadIdx.x;
    // T1: bijective XCD remap (nwg % 8 == 0 for all our launches)
    const int F = blockIdx.y * gridDim.x + blockIdx.x;
    const int cpx = (gridDim.x * gridDim.y) >> 3;
    const int wg = (F & 7) * cpx + (F >> 3);
    const int row0 = (wg / gridDim.x) * 128;
    const int col0 = (wg % gridDim.x) * 128;
    const int w = tid >> 6, lane = tid & 63;
    const int wm = w >> 1, wn = w & 1;
    const int lr = lane & 15, lk = lane >> 4;

    const f32x4 zf = {0.f, 0.f, 0.f, 0.f};
    f32x4 acc[4][4];
#pragma unroll
    for (int m = 0; m < 4; m++)
#pragma unroll
        for (int n = 0; n < 4; n++) acc[m][n] = zf;

    const u16* Ab = A + (size_t)row0 * Kdim;
    const u16* Bb = Bm + (size_t)col0 * Kdim;
    const int srw = lane >> 3;                       // 0..7 within inst
    const int gch = (lane & 7) ^ (srw & 7);          // inverse swizzle on global source
    const size_t grow[4] = {
        (size_t)(w * 32 + 0 * 8 + srw) * Kdim + gch * 8,
        (size_t)(w * 32 + 1 * 8 + srw) * Kdim + gch * 8,
        (size_t)(w * 32 + 2 * 8 + srw) * Kdim + gch * 8,
        (size_t)(w * 32 + 3 * 8 + srw) * Kdim + gch * 8 };
    const int rx = lr & 7;

    for (int k0 = 0; k0 < Kdim; k0 += 64) {
#pragma unroll
        for (int j = 0; j < 4; j++) glds16(Ab + grow[j] + k0, As + (w * 32 + j * 8) * 64);
#pragma unroll
        for (int j = 0; j < 4; j++) glds16(Bb + grow[j] + k0, Bs + (w * 32 + j * 8) * 64);
        __syncthreads();
#pragma unroll
        for (int kk = 0; kk < 2; kk++) {
            const int chx = ((kk * 4 + lk) ^ rx) * 8;
            bf16x8 af[4], bfr[4];
#pragma unroll
            for (int m = 0; m < 4; m++) af[m]  = *(const bf16x8*)&As[(wm * 64 + m * 16 + lr) * 64 + chx];
#pragma unroll
            for (int n = 0; n < 4; n++) bfr[n] = *(const bf16x8*)&Bs[(wn * 64 + n * 16 + lr) * 64 + chx];
#pragma unroll
            for (int m = 0; m < 4; m++)
#pragma unroll
                for (int n = 0; n < 4; n++)
                    acc[m][n] = __builtin_amdgcn_mfma_f32_16x16x32_bf16(af[m], bfr[n], acc[m][n], 0, 0, 0);
        }
        __syncthreads();
    }
#pragma unroll
    for (int m = 0; m < 4; m++)
#pragma unroll
        for (int n = 0; n < 4; n++) {
            const int rr = row0 + wm * 64 + m * 16 + lk * 4;
            const int cc = col0 + wn * 64 + n * 16 + lr;
#pragma unroll
            for (int j = 0; j < 4; j++)
                store_out(Cout + (size_t)(rr + j) * Ndim + cc, acc[m][n][j]);
        }
}

// ---------------- RMSNorm + RoPE for q,k; transpose v -> [bh][d][t] ----------
__global__ __launch_bounds__(256) void norm_rope(const u16* __restrict__ qkv, u16* __restrict__ Qn,
                                                 u16* __restrict__ Kn, u16* __restrict__ Vt,
                                                 const u16* __restrict__ rope) {
    __shared__ u16 sl[3][64][72];
    const int tid = threadIdx.x, bid = blockIdx.x;
    const int tt = bid & 31, bh = bid >> 5;
    const int b = bh >> 4, h = bh & 15;
    const int t0 = tt * 64;
    const size_t base = ((size_t)(b * T_) + t0) * C3_ + h * HD_;
#pragma unroll
    for (int i = 0; i < 6; i++) {
        int c = tid + i * 256;            // 1536 16B chunks
        int p = c >> 9, rc = c & 511;
        int r = rc >> 3, ch = rc & 7;
        *(v4i*)&sl[p][r][ch * 8] = *(const v4i*)(qkv + base + (size_t)r * C3_ + p * C_ + ch * 8);
    }
    __syncthreads();
    const int row = tid >> 2, q4 = tid & 3;  // 4 lanes per row
    const u16* rp = rope + (size_t)(t0 + row) * 64;
#pragma unroll
    for (int p = 0; p < 2; p++) {            // p=0: q, p=1: k
        float ss = 0.f;
#pragma unroll
        for (int j = 0; j < 16; j++) { float v = b2f(sl[p][row][q4 * 16 + j]); ss += v * v; }
        ss += __shfl_xor(ss, 1, 64);
        ss += __shfl_xor(ss, 2, 64);
        const float rms = rsqrtf(ss * (1.f / 64.f) + 1.1920929e-7f);
        u16* outp = (p == 0 ? Qn : Kn) + ((size_t)bh * T_ + t0 + row) * HD_;
#pragma unroll
        for (int j = 0; j < 16; j++) {
            int d = q4 * 16 + j;
            float y;
            if (d < 32) {
                float x1 = b2f(sl[p][row][d]) * rms;
                float x2 = b2f(sl[p][row][d + 32]) * rms;
                y = x1 * b2f(rp[d * 2]) + x2 * b2f(rp[d * 2 + 1]);      // x1*cos + x2*sin
            } else {
                int dd = d - 32;
                float x1 = b2f(sl[p][row][dd]) * rms;
                float x2 = b2f(sl[p][row][d]) * rms;
                y = x2 * b2f(rp[dd * 2]) - x1 * b2f(rp[dd * 2 + 1]);    // x2*cos - x1*sin
            }
            outp[d] = f2b(y);
        }
    }
    const int d = tid >> 2, tq = tid & 3;
    u16* vout = Vt + ((size_t)bh * HD_ + d) * T_ + t0 + tq * 16;
#pragma unroll
    for (int jj = 0; jj < 4; jj++) {
        v4u pk;
#pragma unroll
        for (int j2 = 0; j2 < 4; j2++) pk[j2] = sl[2][tq * 16 + jj * 4 + j2][d];
        *(v4u*)(vout + jj * 4) = pk;
    }
}

// ---------------- causal flash attention v8: glds staging + fixed-m softmax --
// Q,K are RMS-normalized: |S*scale| <= 8 -> exp2 args <= 11.6, P <= ~3000,
// l <= 6e6 — f32/bf16 safe with m == 0. No max chain, no rescale, no ballot.
__global__ __launch_bounds__(256, 4) void attn_fwd8(const u16* __restrict__ Qn, const u16* __restrict__ Kn,
                                                    const u16* __restrict__ Vt, u16* __restrict__ Yb) {
    __shared__ u16 Ks[64 * 64];
    __shared__ u16 Vs[64 * 64];
    const int tid = threadIdx.x;
    const int w = tid >> 6, lane = tid & 63, la = lane & 31, hi = lane >> 5;
    const int gid = blockIdx.x;
    const int bh = gid & 63, qb = 15 - (gid >> 6);
    const int b = bh >> 4, h = bh & 15;
    const int q0w = qb * 128 + w * 32;
    const int q = q0w + la;
    const u16* Qp = Qn + (size_t)bh * T_ * HD_;
    const u16* Kp = Kn + (size_t)bh * T_ * HD_;
    const u16* Vp = Vt + (size_t)bh * HD_ * T_;
    const float SC = 0.125f * 1.44269504088896341f;   // scale * log2(e)

    bf16x8 qf[4];
#pragma unroll
    for (int c = 0; c < 4; c++)
        qf[c] = *(const bf16x8*)(Qp + (size_t)q * HD_ + c * 16 + hi * 8);

    v4i oi; oi[0] = oi[1] = oi[2] = oi[3] = 0x3F803F80;        // bf16 1.0 x8
    const bf16x8 onesf = __builtin_bit_cast(bf16x8, oi);

    f32x16 O0, O1, lsum;
#pragma unroll
    for (int r = 0; r < 16; r++) { O0[r] = 0.f; O1[r] = 0.f; lsum[r] = 0.f; }
    const int lastt = q0w >> 6;
    const int ntile = 2 * qb + 2;
    // glds16 staging: wave w stages rows [w*16, w*16+16) of K and V tiles.
    // Rows are multiples of 8 per inst -> source swizzle chunk = (lane&7)^(lane>>3).
    const int s8 = lane >> 3;
    const int gch = (lane & 7) ^ s8;
    const int Rw = w * 16;
    const size_t kbase = (size_t)(Rw + s8) * HD_ + gch * 8;
    const size_t vbase = (size_t)(Rw + s8) * T_ + gch * 8;
    u16* ldsK = Ks + Rw * 64;
    u16* ldsV = Vs + Rw * 64;
    const int swl = (la & 7) << 3;                               // frag-read XOR

    for (int kt = 0; kt < ntile; kt++) {
        const int kv0 = kt * 64;
        __syncthreads();                     // prev tile's LDS readers done
        glds16(Kp + kbase + (size_t)kv0 * HD_,       ldsK);
        glds16(Kp + kbase + (size_t)(kv0 + 8) * HD_, ldsK + 8 * 64);
        glds16(Vp + vbase + kv0,                     ldsV);
        glds16(Vp + vbase + 8 * T_ + kv0,            ldsV + 8 * 64);
        __syncthreads();                     // published (compiler drains vmcnt)
        if (kv0 > q0w + 31) continue;        // past diagonal; barriers stay matched
        f32x16 s0, s1;
#pragma unroll
        for (int r = 0; r < 16; r++) { s0[r] = 0.f; s1[r] = 0.f; }
#pragma unroll
        for (int c = 0; c < 4; c++) {
            const int cb = c * 16 + hi * 8;
            bf16x8 kfa = *(const bf16x8*)&Ks[la * 64 + (cb ^ swl)];
            bf16x8 kfb = *(const bf16x8*)&Ks[(32 + la) * 64 + (cb ^ swl)];
            s0 = __builtin_amdgcn_mfma_f32_32x32x16_bf16(kfa, qf[c], s0, 0, 0, 0);
            s1 = __builtin_amdgcn_mfma_f32_32x32x16_bf16(kfb, qf[c], s1, 0, 0, 0);
        }
        if (kt == lastt) {
#pragma unroll
            for (int r = 0; r < 16; r++) {
                const int cr = (r & 3) + 8 * (r >> 2) + 4 * hi;
                if (kv0 + cr > q)      s0[r] = -3e38f;
                if (kv0 + 32 + cr > q) s1[r] = -3e38f;
            }
        }
        // fixed-m softmax: P = exp2(S*SC) directly (masked -> exp2(-inf) = 0)
        float p0[16], p1[16];
#pragma unroll
        for (int r = 0; r < 16; r++) {
            p0[r] = exp2f(s0[r] * SC);
            p1[r] = exp2f(s1[r] * SC);
        }
#pragma unroll
        for (int g = 0; g < 2; g++) {
            u32 P2[8];
#pragma unroll
            for (int j = 0; j < 8; j++)
                P2[j] = g ? pk2(p1[2 * j], p1[2 * j + 1]) : pk2(p0[2 * j], p0[2 * j + 1]);
            auto s02 = __builtin_amdgcn_permlane32_swap((int)P2[0], (int)P2[2], false, false);
            auto s13 = __builtin_amdgcn_permlane32_swap((int)P2[1], (int)P2[3], false, false);
            auto s46 = __builtin_amdgcn_permlane32_swap((int)P2[4], (int)P2[6], false, false);
            auto s57 = __builtin_amdgcn_permlane32_swap((int)P2[5], (int)P2[7], false, false);
            v4i w0, w1;
            w0[0] = s02[0]; w0[1] = s13[0]; w0[2] = s02[1]; w0[3] = s13[1];
            w1[0] = s46[0]; w1[1] = s57[0]; w1[2] = s46[1]; w1[3] = s57[1];
            const bf16x8 pa0 = __builtin_bit_cast(bf16x8, w0);
            const bf16x8 pa1 = __builtin_bit_cast(bf16x8, w1);
            // l via ones-row MFMA (row 0 = full key-sum for query la)
            lsum = __builtin_amdgcn_mfma_f32_32x32x16_bf16(onesf, pa0, lsum, 0, 0, 0);
            lsum = __builtin_amdgcn_mfma_f32_32x32x16_bf16(onesf, pa1, lsum, 0, 0, 0);
#pragma unroll
            for (int ks = 0; ks < 2; ks++) {
                const bf16x8 pa = ks ? pa1 : pa0;
                const int cb = g * 32 + ks * 16 + hi * 8;
                bf16x8 vfa = *(const bf16x8*)&Vs[la * 64 + (cb ^ swl)];
                bf16x8 vfb = *(const bf16x8*)&Vs[(32 + la) * 64 + (cb ^ swl)];
                O0 = __builtin_amdgcn_mfma_f32_32x32x16_bf16(vfa, pa, O0, 0, 0, 0);
                O1 = __builtin_amdgcn_mfma_f32_32x32x16_bf16(vfb, pa, O1, 0, 0, 0);
            }
        }
    }
    const float inv = 1.f / lsum[0];
    u16* yrow = Yb + ((size_t)(b * T_) + q) * C_ + h * HD_;
#pragma unroll
    for (int r4 = 0; r4 < 4; r4++) {
        u32x2 st0, st1;
        st0[0] = pk2(O0[r4 * 4 + 0] * inv, O0[r4 * 4 + 1] * inv);
        st0[1] = pk2(O0[r4 * 4 + 2] * inv, O0[r4 * 4 + 3] * inv);
        st1[0] = pk2(O1[r4 * 4 + 0] * inv, O1[r4 * 4 + 1] * inv);
        st1[1] = pk2(O1[r4 * 4 + 2] * inv, O1[r4 * 4 + 3] * inv);
        *(u32x2*)(yrow + r4 * 8 + hi * 4)      = st0;
        *(u32x2*)(yrow + 32 + r4 * 8 + hi * 4) = st1;
    }
}

extern "C" void kernel_launch(void* const* d_in, const int* in_sizes, int n_in,
                              void* d_out, int out_size, void* d_ws, size_t ws_size,
                              hipStream_t stream) {
    const float* x      = (const float*)d_in[0];
    const float* w_attn = (const float*)d_in[1];
    const float* w_proj = (const float*)d_in[2];
    float* out = (float*)d_out;
    char* ws = (char*)d_ws;
    // lifetime-overlapped workspace, peak ~104.3 MB
    u16* Wpb = (u16*)(ws + 0);              // 2 MB,   live: all
    u16* Rp  = (u16*)(ws + 2097152);        // 256 KB, live: -> norm
    u16* Xb  = (u16*)(ws + 2359296);        // 16 MB,  live: -> gemm1
    u16* Wab = (u16*)(ws + 19136512);       // 6 MB,   live: -> gemm1
    u16* QKV = (u16*)(ws + 25427968);       // 48 MB,  live: gemm1 -> norm
    u16* Qn  = (u16*)(ws + 2359296);        // 16 MB,  over Xb (dead), norm -> attn
    u16* Kn  = (u16*)(ws + 75759616);       // 16 MB,  norm -> attn
    u16* Vt  = (u16*)(ws + 92536832);       // 16 MB,  norm -> attn  [bh][d][t]
    u16* Yb  = (u16*)(ws + 25427968);       // 16 MB,  over QKV (dead), attn -> gemm2

    cast_f32_bf16<<<8192, 256, 0, stream>>>(x, Xb, 2097152);
    cast_f32_bf16<<<3072, 256, 0, stream>>>(w_attn, Wab, 786432);
    cast_f32_bf16<<<1024, 256, 0, stream>>>(w_proj, Wpb, 262144);
    rope_tab<<<256, 256, 0, stream>>>(Rp);
    gemm_bt5<u16><<<dim3(24, 64), 256, 0, stream>>>(Xb, Wab, QKV, 8192, 3072, 1024);
    norm_rope<<<2048, 256, 0, stream>>>(QKV, Qn, Kn, Vt, Rp);
    attn_fwd8<<<1024, 256, 0, stream>>>(Qn, Kn, Vt, Yb);
    gemm_bt5<float><<<dim3(8, 64), 256, 0, stream>>>(Yb, Wpb, out, 8192, 1024, 1024);
}

// Round 12
// 237.474 us; speedup vs baseline: 1.1207x; 1.0097x over previous
//
#include <hip/hip_runtime.h>

typedef unsigned short u16;
typedef unsigned int u32;
typedef __attribute__((ext_vector_type(4))) int v4i;
typedef __attribute__((ext_vector_type(4))) float f32x4;
typedef __attribute__((ext_vector_type(16))) float f32x16;
typedef __attribute__((ext_vector_type(4))) u16 v4u;
typedef __attribute__((ext_vector_type(2))) u32 u32x2;
typedef __attribute__((ext_vector_type(8))) __bf16 bf16x8;

#define B_ 4
#define T_ 2048
#define C_ 1024
#define H_ 16
#define HD_ 64
#define C3_ 3072

__device__ __forceinline__ u16 f2b(float f) {
    unsigned u = __builtin_bit_cast(unsigned, f);
    u += 0x7FFFu + ((u >> 16) & 1u);
    return (u16)(u >> 16);
}
__device__ __forceinline__ float b2f(u16 h) {
    unsigned u = ((unsigned)h) << 16;
    return __builtin_bit_cast(float, u);
}
__device__ __forceinline__ u32 pk2(float lo, float hi) {
    __bf16 a = (__bf16)lo, b = (__bf16)hi;
    return (u32)__builtin_bit_cast(u16, a) | ((u32)__builtin_bit_cast(u16, b) << 16);
}
// async global->LDS, 16B per lane; LDS dest = uniform base + lane*16
__device__ __forceinline__ void glds16(const u16* g, u16* l) {
    __builtin_amdgcn_global_load_lds((const __attribute__((address_space(1))) void*)g,
                                     (__attribute__((address_space(3))) void*)l, 16, 0, 0);
}

// ---------------- cast f32 -> bf16 ----------------
__global__ __launch_bounds__(256) void cast_f32_bf16(const float* __restrict__ in,
                                                     u16* __restrict__ out, int n4) {
    int i = blockIdx.x * 256 + threadIdx.x;
    if (i >= n4) return;
    f32x4 v = *(const f32x4*)(in + (size_t)i * 4);
    v4u o;
    o[0] = f2b(v[0]); o[1] = f2b(v[1]); o[2] = f2b(v[2]); o[3] = f2b(v[3]);
    *(v4u*)(out + (size_t)i * 4) = o;
}

// ---------------- rope table ----------------
__global__ __launch_bounds__(256) void rope_tab(u16* __restrict__ rope) {
    int id = blockIdx.x * 256 + threadIdx.x;   // T_*32 entries
    int t = id >> 5, j = id & 31;
    float invf = exp2f(-(float)j * (13.287712379549449f / 32.0f));  // 10000^(-j/32)
    float fr = (float)t * invf;
    float s, c;
    sincosf(fr, &s, &c);
    rope[id * 2]     = f2b(c);
    rope[id * 2 + 1] = f2b(s);
}

// ---------------- GEMM v5: BK=64 glds + XOR swizzle + bijective XCD remap ----
__device__ __forceinline__ void store_out(u16* p, float v)   { *p = f2b(v); }
__device__ __forceinline__ void store_out(float* p, float v) { *p = v; }

template <typename OutT>
__global__ __launch_bounds__(256) void gemm_bt5(const u16* __restrict__ A, const u16* __restrict__ Bm,
                                                OutT* __restrict__ Cout, int Mdim, int Ndim, int Kdim) {
    __shared__ u16 As[8192];     // [128][64] swizzled, 16 KB
    __shared__ u16 Bs[8192];
    const int tid = threadIdx.x;
    // T1: bijective XCD remap (nwg % 8 == 0 for all our launches)
    const int F = blockIdx.y * gridDim.x + blockIdx.x;
    const int cpx = (gridDim.x * gridDim.y) >> 3;
    const int wg = (F & 7) * cpx + (F >> 3);
    const int row0 = (wg / gridDim.x) * 128;
    const int col0 = (wg % gridDim.x) * 128;
    const int w = tid >> 6, lane = tid & 63;
    const int wm = w >> 1, wn = w & 1;
    const int lr = lane & 15, lk = lane >> 4;

    const f32x4 zf = {0.f, 0.f, 0.f, 0.f};
    f32x4 acc[4][4];
#pragma unroll
    for (int m = 0; m < 4; m++)
#pragma unroll
        for (int n = 0; n < 4; n++) acc[m][n] = zf;

    const u16* Ab = A + (size_t)row0 * Kdim;
    const u16* Bb = Bm + (size_t)col0 * Kdim;
    const int srw = lane >> 3;                       // 0..7 within inst
    const int gch = (lane & 7) ^ (srw & 7);          // inverse swizzle on global source
    const size_t grow[4] = {
        (size_t)(w * 32 + 0 * 8 + srw) * Kdim + gch * 8,
        (size_t)(w * 32 + 1 * 8 + srw) * Kdim + gch * 8,
        (size_t)(w * 32 + 2 * 8 + srw) * Kdim + gch * 8,
        (size_t)(w * 32 + 3 * 8 + srw) * Kdim + gch * 8 };
    const int rx = lr & 7;

    for (int k0 = 0; k0 < Kdim; k0 += 64) {
#pragma unroll
        for (int j = 0; j < 4; j++) glds16(Ab + grow[j] + k0, As + (w * 32 + j * 8) * 64);
#pragma unroll
        for (int j = 0; j < 4; j++) glds16(Bb + grow[j] + k0, Bs + (w * 32 + j * 8) * 64);
        __syncthreads();
#pragma unroll
        for (int kk = 0; kk < 2; kk++) {
            const int chx = ((kk * 4 + lk) ^ rx) * 8;
            bf16x8 af[4], bfr[4];
#pragma unroll
            for (int m = 0; m < 4; m++) af[m]  = *(const bf16x8*)&As[(wm * 64 + m * 16 + lr) * 64 + chx];
#pragma unroll
            for (int n = 0; n < 4; n++) bfr[n] = *(const bf16x8*)&Bs[(wn * 64 + n * 16 + lr) * 64 + chx];
#pragma unroll
            for (int m = 0; m < 4; m++)
#pragma unroll
                for (int n = 0; n < 4; n++)
                    acc[m][n] = __builtin_amdgcn_mfma_f32_16x16x32_bf16(af[m], bfr[n], acc[m][n], 0, 0, 0);
        }
        __syncthreads();
    }
#pragma unroll
    for (int m = 0; m < 4; m++)
#pragma unroll
        for (int n = 0; n < 4; n++) {
            const int rr = row0 + wm * 64 + m * 16 + lk * 4;
            const int cc = col0 + wn * 64 + n * 16 + lr;
#pragma unroll
            for (int j = 0; j < 4; j++)
                store_out(Cout + (size_t)(rr + j) * Ndim + cc, acc[m][n][j]);
        }
}

// ---------------- RMSNorm + RoPE for q,k; transpose v -> [bh][d][t] ----------
// Q output is PRE-SCALED by 0.125*log2(e) so attn's softmax is exp2(S) directly.
__global__ __launch_bounds__(256) void norm_rope(const u16* __restrict__ qkv, u16* __restrict__ Qn,
                                                 u16* __restrict__ Kn, u16* __restrict__ Vt,
                                                 const u16* __restrict__ rope) {
    __shared__ u16 sl[3][64][72];
    const int tid = threadIdx.x, bid = blockIdx.x;
    const int tt = bid & 31, bh = bid >> 5;
    const int b = bh >> 4, h = bh & 15;
    const int t0 = tt * 64;
    const size_t base = ((size_t)(b * T_) + t0) * C3_ + h * HD_;
#pragma unroll
    for (int i = 0; i < 6; i++) {
        int c = tid + i * 256;            // 1536 16B chunks
        int p = c >> 9, rc = c & 511;
        int r = rc >> 3, ch = rc & 7;
        *(v4i*)&sl[p][r][ch * 8] = *(const v4i*)(qkv + base + (size_t)r * C3_ + p * C_ + ch * 8);
    }
    __syncthreads();
    const int row = tid >> 2, q4 = tid & 3;  // 4 lanes per row
    const u16* rp = rope + (size_t)(t0 + row) * 64;
#pragma unroll
    for (int p = 0; p < 2; p++) {            // p=0: q, p=1: k
        float ss = 0.f;
#pragma unroll
        for (int j = 0; j < 16; j++) { float v = b2f(sl[p][row][q4 * 16 + j]); ss += v * v; }
        ss += __shfl_xor(ss, 1, 64);
        ss += __shfl_xor(ss, 2, 64);
        const float rms = rsqrtf(ss * (1.f / 64.f) + 1.1920929e-7f);
        const float oscale = p == 0 ? 0.18033688011112042f : 1.0f;   // q: scale*log2(e)
        u16* outp = (p == 0 ? Qn : Kn) + ((size_t)bh * T_ + t0 + row) * HD_;
#pragma unroll
        for (int j = 0; j < 16; j++) {
            int d = q4 * 16 + j;
            float y;
            if (d < 32) {
                float x1 = b2f(sl[p][row][d]) * rms;
                float x2 = b2f(sl[p][row][d + 32]) * rms;
                y = x1 * b2f(rp[d * 2]) + x2 * b2f(rp[d * 2 + 1]);      // x1*cos + x2*sin
            } else {
                int dd = d - 32;
                float x1 = b2f(sl[p][row][dd]) * rms;
                float x2 = b2f(sl[p][row][d]) * rms;
                y = x2 * b2f(rp[dd * 2]) - x1 * b2f(rp[dd * 2 + 1]);    // x2*cos - x1*sin
            }
            outp[d] = f2b(y * oscale);
        }
    }
    const int d = tid >> 2, tq = tid & 3;
    u16* vout = Vt + ((size_t)bh * HD_ + d) * T_ + t0 + tq * 16;
#pragma unroll
    for (int jj = 0; jj < 4; jj++) {
        v4u pk;
#pragma unroll
        for (int j2 = 0; j2 < 4; j2++) pk[j2] = sl[2][tq * 16 + jj * 4 + j2][d];
        *(v4u*)(vout + jj * 4) = pk;
    }
}

// ---------------- causal flash attention v9: double-buffered 2-phase pipeline
// STAGE(next) || COMPUTE(cur); ONE vmcnt(0)+barrier per tile (T3 minimum form).
// glds16 prefetch uses no VGPRs -> no spill risk. Q pre-scaled: P = exp2(S).
__global__ __launch_bounds__(256, 4) void attn_fwd9(const u16* __restrict__ Qn, const u16* __restrict__ Kn,
                                                    const u16* __restrict__ Vt, u16* __restrict__ Yb) {
    __shared__ u16 Ks[2][4096];
    __shared__ u16 Vs[2][4096];
    const int tid = threadIdx.x;
    const int w = tid >> 6, lane = tid & 63, la = lane & 31, hi = lane >> 5;
    const int gid = blockIdx.x;
    const int bh = gid & 63, qb = 15 - (gid >> 6);
    const int b = bh >> 4, h = bh & 15;
    const int q0w = qb * 128 + w * 32;
    const int q = q0w + la;
    const u16* Qp = Qn + (size_t)bh * T_ * HD_;
    const u16* Kp = Kn + (size_t)bh * T_ * HD_;
    const u16* Vp = Vt + (size_t)bh * HD_ * T_;

    bf16x8 qf[4];
#pragma unroll
    for (int c = 0; c < 4; c++)
        qf[c] = *(const bf16x8*)(Qp + (size_t)q * HD_ + c * 16 + hi * 8);

    v4i oi; oi[0] = oi[1] = oi[2] = oi[3] = 0x3F803F80;        // bf16 1.0 x8
    const bf16x8 onesf = __builtin_bit_cast(bf16x8, oi);

    f32x16 O0, O1, lsum;
#pragma unroll
    for (int r = 0; r < 16; r++) { O0[r] = 0.f; O1[r] = 0.f; lsum[r] = 0.f; }
    const int lastt = q0w >> 6;
    const int ntile = 2 * qb + 2;              // always even
    // glds16 staging: wave w stages rows [w*16, w*16+16) of K and V tiles.
    const int s8 = lane >> 3;
    const int gch = (lane & 7) ^ s8;
    const int Rw = w * 16;
    const size_t kbase = (size_t)(Rw + s8) * HD_ + gch * 8;
    const size_t vbase = (size_t)(Rw + s8) * T_ + gch * 8;
    const int swl = (la & 7) << 3;                               // frag-read XOR

    auto STAGE = [&](int bi, int kv0) {
        glds16(Kp + kbase + (size_t)kv0 * HD_,       &Ks[bi][Rw * 64]);
        glds16(Kp + kbase + (size_t)(kv0 + 8) * HD_, &Ks[bi][Rw * 64 + 512]);
        glds16(Vp + vbase + kv0,                     &Vs[bi][Rw * 64]);
        glds16(Vp + vbase + 8 * T_ + kv0,            &Vs[bi][Rw * 64 + 512]);
    };
    auto COMPUTE = [&](int bi, int kt) {
        const int kv0 = kt * 64;
        f32x16 s0, s1;
#pragma unroll
        for (int r = 0; r < 16; r++) { s0[r] = 0.f; s1[r] = 0.f; }
#pragma unroll
        for (int c = 0; c < 4; c++) {
            const int cb = c * 16 + hi * 8;
            bf16x8 kfa = *(const bf16x8*)&Ks[bi][la * 64 + (cb ^ swl)];
            bf16x8 kfb = *(const bf16x8*)&Ks[bi][(32 + la) * 64 + (cb ^ swl)];
            s0 = __builtin_amdgcn_mfma_f32_32x32x16_bf16(kfa, qf[c], s0, 0, 0, 0);
            s1 = __builtin_amdgcn_mfma_f32_32x32x16_bf16(kfb, qf[c], s1, 0, 0, 0);
        }
        if (kt == lastt) {
#pragma unroll
            for (int r = 0; r < 16; r++) {
                const int cr = (r & 3) + 8 * (r >> 2) + 4 * hi;
                if (kv0 + cr > q)      s0[r] = -3e38f;
                if (kv0 + 32 + cr > q) s1[r] = -3e38f;
            }
        }
        // fixed-m softmax with pre-scaled Q: P = exp2(S); masked -> 0
        float p0[16], p1[16];
#pragma unroll
        for (int r = 0; r < 16; r++) {
            p0[r] = exp2f(s0[r]);
            p1[r] = exp2f(s1[r]);
        }
#pragma unroll
        for (int g = 0; g < 2; g++) {
            u32 P2[8];
#pragma unroll
            for (int j = 0; j < 8; j++)
                P2[j] = g ? pk2(p1[2 * j], p1[2 * j + 1]) : pk2(p0[2 * j], p0[2 * j + 1]);
            auto s02 = __builtin_amdgcn_permlane32_swap((int)P2[0], (int)P2[2], false, false);
            auto s13 = __builtin_amdgcn_permlane32_swap((int)P2[1], (int)P2[3], false, false);
            auto s46 = __builtin_amdgcn_permlane32_swap((int)P2[4], (int)P2[6], false, false);
            auto s57 = __builtin_amdgcn_permlane32_swap((int)P2[5], (int)P2[7], false, false);
            v4i w0, w1;
            w0[0] = s02[0]; w0[1] = s13[0]; w0[2] = s02[1]; w0[3] = s13[1];
            w1[0] = s46[0]; w1[1] = s57[0]; w1[2] = s46[1]; w1[3] = s57[1];
            const bf16x8 pa0 = __builtin_bit_cast(bf16x8, w0);
            const bf16x8 pa1 = __builtin_bit_cast(bf16x8, w1);
            lsum = __builtin_amdgcn_mfma_f32_32x32x16_bf16(onesf, pa0, lsum, 0, 0, 0);
            lsum = __builtin_amdgcn_mfma_f32_32x32x16_bf16(onesf, pa1, lsum, 0, 0, 0);
#pragma unroll
            for (int ks = 0; ks < 2; ks++) {
                const bf16x8 pa = ks ? pa1 : pa0;
                const int cb = g * 32 + ks * 16 + hi * 8;
                bf16x8 vfa = *(const bf16x8*)&Vs[bi][la * 64 + (cb ^ swl)];
                bf16x8 vfb = *(const bf16x8*)&Vs[bi][(32 + la) * 64 + (cb ^ swl)];
                O0 = __builtin_amdgcn_mfma_f32_32x32x16_bf16(vfa, pa, O0, 0, 0, 0);
                O1 = __builtin_amdgcn_mfma_f32_32x32x16_bf16(vfb, pa, O1, 0, 0, 0);
            }
        }
    };

    STAGE(0, 0);
    for (int t = 0; t < ntile; t += 2) {
        __syncthreads();                       // drains vmcnt -> buf0 ready; buf1 readers done
        STAGE(1, (t + 1) * 64);                // prefetch flies under compute (t+1 < ntile always)
        if (t <= lastt) COMPUTE(0, t);
        __syncthreads();                       // drains vmcnt -> buf1 ready; buf0 readers done
        if (t + 2 < ntile) STAGE(0, (t + 2) * 64);
        if (t + 1 <= lastt) COMPUTE(1, t + 1);
    }

    const float inv = 1.f / lsum[0];
    u16* yrow = Yb + ((size_t)(b * T_) + q) * C_ + h * HD_;
#pragma unroll
    for (int r4 = 0; r4 < 4; r4++) {
        u32x2 st0, st1;
        st0[0] = pk2(O0[r4 * 4 + 0] * inv, O0[r4 * 4 + 1] * inv);
        st0[1] = pk2(O0[r4 * 4 + 2] * inv, O0[r4 * 4 + 3] * inv);
        st1[0] = pk2(O1[r4 * 4 + 0] * inv, O1[r4 * 4 + 1] * inv);
        st1[1] = pk2(O1[r4 * 4 + 2] * inv, O1[r4 * 4 + 3] * inv);
        *(u32x2*)(yrow + r4 * 8 + hi * 4)      = st0;
        *(u32x2*)(yrow + 32 + r4 * 8 + hi * 4) = st1;
    }
}

extern "C" void kernel_launch(void* const* d_in, const int* in_sizes, int n_in,
                              void* d_out, int out_size, void* d_ws, size_t ws_size,
                              hipStream_t stream) {
    const float* x      = (const float*)d_in[0];
    const float* w_attn = (const float*)d_in[1];
    const float* w_proj = (const float*)d_in[2];
    float* out = (float*)d_out;
    char* ws = (char*)d_ws;
    // lifetime-overlapped workspace, peak ~104.3 MB
    u16* Wpb = (u16*)(ws + 0);              // 2 MB,   live: all
    u16* Rp  = (u16*)(ws + 2097152);        // 256 KB, live: -> norm
    u16* Xb  = (u16*)(ws + 2359296);        // 16 MB,  live: -> gemm1
    u16* Wab = (u16*)(ws + 19136512);       // 6 MB,   live: -> gemm1
    u16* QKV = (u16*)(ws + 25427968);       // 48 MB,  live: gemm1 -> norm
    u16* Qn  = (u16*)(ws + 2359296);        // 16 MB,  over Xb (dead), norm -> attn
    u16* Kn  = (u16*)(ws + 75759616);       // 16 MB,  norm -> attn
    u16* Vt  = (u16*)(ws + 92536832);       // 16 MB,  norm -> attn  [bh][d][t]
    u16* Yb  = (u16*)(ws + 25427968);       // 16 MB,  over QKV (dead), attn -> gemm2

    cast_f32_bf16<<<8192, 256, 0, stream>>>(x, Xb, 2097152);
    cast_f32_bf16<<<3072, 256, 0, stream>>>(w_attn, Wab, 786432);
    cast_f32_bf16<<<1024, 256, 0, stream>>>(w_proj, Wpb, 262144);
    rope_tab<<<256, 256, 0, stream>>>(Rp);
    gemm_bt5<u16><<<dim3(24, 64), 256, 0, stream>>>(Xb, Wab, QKV, 8192, 3072, 1024);
    norm_rope<<<2048, 256, 0, stream>>>(QKV, Qn, Kn, Vt, Rp);
    attn_fwd9<<<1024, 256, 0, stream>>>(Qn, Kn, Vt, Yb);
    gemm_bt5<float><<<dim3(8, 64), 256, 0, stream>>>(Yb, Wpb, out, 8192, 1024, 1024);
}

// Round 13
// 187.484 us; speedup vs baseline: 1.4195x; 1.2666x over previous
//
#include <hip/hip_runtime.h>

typedef unsigned short u16;
typedef unsigned int u32;
typedef __attribute__((ext_vector_type(4))) int v4i;
typedef __attribute__((ext_vector_type(4))) float f32x4;
typedef __attribute__((ext_vector_type(16))) float f32x16;
typedef __attribute__((ext_vector_type(4))) u16 v4u;
typedef __attribute__((ext_vector_type(2))) u32 u32x2;
typedef __attribute__((ext_vector_type(8))) __bf16 bf16x8;

#define B_ 4
#define T_ 2048
#define C_ 1024
#define H_ 16
#define HD_ 64
#define C3_ 3072

__device__ __forceinline__ u16 f2b(float f) {
    unsigned u = __builtin_bit_cast(unsigned, f);
    u += 0x7FFFu + ((u >> 16) & 1u);
    return (u16)(u >> 16);
}
__device__ __forceinline__ float b2f(u16 h) {
    unsigned u = ((unsigned)h) << 16;
    return __builtin_bit_cast(float, u);
}
__device__ __forceinline__ u32 pk2(float lo, float hi) {
    __bf16 a = (__bf16)lo, b = (__bf16)hi;
    return (u32)__builtin_bit_cast(u16, a) | ((u32)__builtin_bit_cast(u16, b) << 16);
}
// async global->LDS, 16B per lane; LDS dest = uniform base + lane*16
__device__ __forceinline__ void glds16(const u16* g, u16* l) {
    __builtin_amdgcn_global_load_lds((const __attribute__((address_space(1))) void*)g,
                                     (__attribute__((address_space(3))) void*)l, 16, 0, 0);
}

// ---------------- cast f32 -> bf16 ----------------
__global__ __launch_bounds__(256) void cast_f32_bf16(const float* __restrict__ in,
                                                     u16* __restrict__ out, int n4) {
    int i = blockIdx.x * 256 + threadIdx.x;
    if (i >= n4) return;
    f32x4 v = *(const f32x4*)(in + (size_t)i * 4);
    v4u o;
    o[0] = f2b(v[0]); o[1] = f2b(v[1]); o[2] = f2b(v[2]); o[3] = f2b(v[3]);
    *(v4u*)(out + (size_t)i * 4) = o;
}

// ---------------- rope table ----------------
__global__ __launch_bounds__(256) void rope_tab(u16* __restrict__ rope) {
    int id = blockIdx.x * 256 + threadIdx.x;   // T_*32 entries
    int t = id >> 5, j = id & 31;
    float invf = exp2f(-(float)j * (13.287712379549449f / 32.0f));  // 10000^(-j/32)
    float fr = (float)t * invf;
    float s, c;
    sincosf(fr, &s, &c);
    rope[id * 2]     = f2b(c);
    rope[id * 2 + 1] = f2b(s);
}

// ---------------- GEMM v5: BK=64 glds + XOR swizzle + bijective XCD remap ----
__device__ __forceinline__ void store_out(u16* p, float v)   { *p = f2b(v); }
__device__ __forceinline__ void store_out(float* p, float v) { *p = v; }

template <typename OutT>
__global__ __launch_bounds__(256) void gemm_bt5(const u16* __restrict__ A, const u16* __restrict__ Bm,
                                                OutT* __restrict__ Cout, int Mdim, int Ndim, int Kdim) {
    __shared__ u16 As[8192];     // [128][64] swizzled, 16 KB
    __shared__ u16 Bs[8192];
    const int tid = threadIdx.x;
    // T1: bijective XCD remap (nwg % 8 == 0 for all our launches)
    const int F = blockIdx.y * gridDim.x + blockIdx.x;
    const int cpx = (gridDim.x * gridDim.y) >> 3;
    const int wg = (F & 7) * cpx + (F >> 3);
    const int row0 = (wg / gridDim.x) * 128;
    const int col0 = (wg % gridDim.x) * 128;
    const int w = tid >> 6, lane = tid & 63;
    const int wm = w >> 1, wn = w & 1;
    const int lr = lane & 15, lk = lane >> 4;

    const f32x4 zf = {0.f, 0.f, 0.f, 0.f};
    f32x4 acc[4][4];
#pragma unroll
    for (int m = 0; m < 4; m++)
#pragma unroll
        for (int n = 0; n < 4; n++) acc[m][n] = zf;

    const u16* Ab = A + (size_t)row0 * Kdim;
    const u16* Bb = Bm + (size_t)col0 * Kdim;
    const int srw = lane >> 3;                       // 0..7 within inst
    const int gch = (lane & 7) ^ (srw & 7);          // inverse swizzle on global source
    const size_t grow[4] = {
        (size_t)(w * 32 + 0 * 8 + srw) * Kdim + gch * 8,
        (size_t)(w * 32 + 1 * 8 + srw) * Kdim + gch * 8,
        (size_t)(w * 32 + 2 * 8 + srw) * Kdim + gch * 8,
        (size_t)(w * 32 + 3 * 8 + srw) * Kdim + gch * 8 };
    const int rx = lr & 7;

    for (int k0 = 0; k0 < Kdim; k0 += 64) {
#pragma unroll
        for (int j = 0; j < 4; j++) glds16(Ab + grow[j] + k0, As + (w * 32 + j * 8) * 64);
#pragma unroll
        for (int j = 0; j < 4; j++) glds16(Bb + grow[j] + k0, Bs + (w * 32 + j * 8) * 64);
        __syncthreads();
#pragma unroll
        for (int kk = 0; kk < 2; kk++) {
            const int chx = ((kk * 4 + lk) ^ rx) * 8;
            bf16x8 af[4], bfr[4];
#pragma unroll
            for (int m = 0; m < 4; m++) af[m]  = *(const bf16x8*)&As[(wm * 64 + m * 16 + lr) * 64 + chx];
#pragma unroll
            for (int n = 0; n < 4; n++) bfr[n] = *(const bf16x8*)&Bs[(wn * 64 + n * 16 + lr) * 64 + chx];
#pragma unroll
            for (int m = 0; m < 4; m++)
#pragma unroll
                for (int n = 0; n < 4; n++)
                    acc[m][n] = __builtin_amdgcn_mfma_f32_16x16x32_bf16(af[m], bfr[n], acc[m][n], 0, 0, 0);
        }
        __syncthreads();
    }
#pragma unroll
    for (int m = 0; m < 4; m++)
#pragma unroll
        for (int n = 0; n < 4; n++) {
            const int rr = row0 + wm * 64 + m * 16 + lk * 4;
            const int cc = col0 + wn * 64 + n * 16 + lr;
#pragma unroll
            for (int j = 0; j < 4; j++)
                store_out(Cout + (size_t)(rr + j) * Ndim + cc, acc[m][n][j]);
        }
}

// ---------------- RMSNorm + RoPE v3: LDS-free Q/K (16B stores), LDS V-transpose
// Block = 256 thr = 32 t-rows x 8 lanes. Grid = 64bh x 64tt = 4096.
// Q output PRE-SCALED by 0.125*log2(e) (attn uses exp2(S) directly).
__global__ __launch_bounds__(256) void norm_rope3(const u16* __restrict__ qkv, u16* __restrict__ Qn,
                                                  u16* __restrict__ Kn, u16* __restrict__ Vt,
                                                  const u16* __restrict__ rope) {
    __shared__ u16 sl[32][72];
    const int tid = threadIdx.x, bid = blockIdx.x;
    const int tt = bid & 63, bh = bid >> 6;
    const int b = bh >> 4, h = bh & 15;
    const int rl = tid >> 3, g = tid & 7;
    const int t = tt * 32 + rl;
    const size_t rowbase = ((size_t)(b * T_) + t) * C3_ + h * HD_;
    const size_t obase = ((size_t)bh * T_ + t) * HD_ + g * 8;
    // stage V tile [32 t][64 d] into LDS (16B coalesced loads)
    *(v4i*)&sl[rl][g * 8] = *(const v4i*)(qkv + rowbase + 2 * C_ + g * 8);
    const u16* rp = rope + (size_t)t * 64;
#pragma unroll
    for (int p = 0; p < 2; p++) {            // p=0: q, p=1: k
        v4i rw = *(const v4i*)(qkv + rowbase + p * C_ + g * 8);
        float xv[8];
#pragma unroll
        for (int c = 0; c < 4; c++) {
            unsigned u = (unsigned)rw[c];
            xv[c * 2]     = b2f((u16)(u & 0xFFFFu));
            xv[c * 2 + 1] = b2f((u16)(u >> 16));
        }
        float ss = 0.f;
#pragma unroll
        for (int j = 0; j < 8; j++) ss += xv[j] * xv[j];
        ss += __shfl_xor(ss, 1, 64);
        ss += __shfl_xor(ss, 2, 64);
        ss += __shfl_xor(ss, 4, 64);
        const float rms = rsqrtf(ss * (1.f / 64.f) + 1.1920929e-7f);
        const float oscale = p == 0 ? 0.18033688011112042f : 1.0f;   // q: scale*log2(e)
#pragma unroll
        for (int j = 0; j < 8; j++) xv[j] *= rms;
        float xp[8];
#pragma unroll
        for (int j = 0; j < 8; j++) xp[j] = __shfl_xor(xv[j], 4, 64);
        float ys[8];
        if (g < 4) {
#pragma unroll
            for (int j = 0; j < 8; j++) {      // d = 8g+j < 32: y = x1*cos + x2*sin
                int d = g * 8 + j;
                ys[j] = xv[j] * b2f(rp[d * 2]) + xp[j] * b2f(rp[d * 2 + 1]);
            }
        } else {
#pragma unroll
            for (int j = 0; j < 8; j++) {      // dd = d-32: y = x2*cos - x1*sin
                int dd = (g - 4) * 8 + j;
                ys[j] = xv[j] * b2f(rp[dd * 2]) - xp[j] * b2f(rp[dd * 2 + 1]);
            }
        }
        v4i ov;
#pragma unroll
        for (int c = 0; c < 4; c++)
            ov[c] = (int)((unsigned)f2b(ys[c * 2] * oscale) | ((unsigned)f2b(ys[c * 2 + 1] * oscale) << 16));
        *(v4i*)((p ? Kn : Qn) + obase) = ov;
    }
    __syncthreads();
    // V^T write: lane (d = tid>>2, tq = tid&3) packs 8 t-values, 16B store
    const int d = tid >> 2, tq = tid & 3;
    v4i ov;
#pragma unroll
    for (int c = 0; c < 4; c++)
        ov[c] = (int)((unsigned)sl[tq * 8 + c * 2][d] | ((unsigned)sl[tq * 8 + c * 2 + 1][d] << 16));
    *(v4i*)(Vt + ((size_t)bh * HD_ + d) * T_ + tt * 32 + tq * 8) = ov;
}

// ---------------- causal flash attention v9: double-buffered 2-phase pipeline
// STAGE(next) || COMPUTE(cur); ONE vmcnt(0)+barrier per tile (T3 minimum form).
__global__ __launch_bounds__(256, 4) void attn_fwd9(const u16* __restrict__ Qn, const u16* __restrict__ Kn,
                                                    const u16* __restrict__ Vt, u16* __restrict__ Yb) {
    __shared__ u16 Ks[2][4096];
    __shared__ u16 Vs[2][4096];
    const int tid = threadIdx.x;
    const int w = tid >> 6, lane = tid & 63, la = lane & 31, hi = lane >> 5;
    const int gid = blockIdx.x;
    const int bh = gid & 63, qb = 15 - (gid >> 6);
    const int b = bh >> 4, h = bh & 15;
    const int q0w = qb * 128 + w * 32;
    const int q = q0w + la;
    const u16* Qp = Qn + (size_t)bh * T_ * HD_;
    const u16* Kp = Kn + (size_t)bh * T_ * HD_;
    const u16* Vp = Vt + (size_t)bh * HD_ * T_;

    bf16x8 qf[4];
#pragma unroll
    for (int c = 0; c < 4; c++)
        qf[c] = *(const bf16x8*)(Qp + (size_t)q * HD_ + c * 16 + hi * 8);

    v4i oi; oi[0] = oi[1] = oi[2] = oi[3] = 0x3F803F80;        // bf16 1.0 x8
    const bf16x8 onesf = __builtin_bit_cast(bf16x8, oi);

    f32x16 O0, O1, lsum;
#pragma unroll
    for (int r = 0; r < 16; r++) { O0[r] = 0.f; O1[r] = 0.f; lsum[r] = 0.f; }
    const int lastt = q0w >> 6;
    const int ntile = 2 * qb + 2;              // always even
    const int s8 = lane >> 3;
    const int gch = (lane & 7) ^ s8;
    const int Rw = w * 16;
    const size_t kbase = (size_t)(Rw + s8) * HD_ + gch * 8;
    const size_t vbase = (size_t)(Rw + s8) * T_ + gch * 8;
    const int swl = (la & 7) << 3;                               // frag-read XOR

    auto STAGE = [&](int bi, int kv0) {
        glds16(Kp + kbase + (size_t)kv0 * HD_,       &Ks[bi][Rw * 64]);
        glds16(Kp + kbase + (size_t)(kv0 + 8) * HD_, &Ks[bi][Rw * 64 + 512]);
        glds16(Vp + vbase + kv0,                     &Vs[bi][Rw * 64]);
        glds16(Vp + vbase + 8 * T_ + kv0,            &Vs[bi][Rw * 64 + 512]);
    };
    auto COMPUTE = [&](int bi, int kt) {
        const int kv0 = kt * 64;
        f32x16 s0, s1;
#pragma unroll
        for (int r = 0; r < 16; r++) { s0[r] = 0.f; s1[r] = 0.f; }
#pragma unroll
        for (int c = 0; c < 4; c++) {
            const int cb = c * 16 + hi * 8;
            bf16x8 kfa = *(const bf16x8*)&Ks[bi][la * 64 + (cb ^ swl)];
            bf16x8 kfb = *(const bf16x8*)&Ks[bi][(32 + la) * 64 + (cb ^ swl)];
            s0 = __builtin_amdgcn_mfma_f32_32x32x16_bf16(kfa, qf[c], s0, 0, 0, 0);
            s1 = __builtin_amdgcn_mfma_f32_32x32x16_bf16(kfb, qf[c], s1, 0, 0, 0);
        }
        if (kt == lastt) {
#pragma unroll
            for (int r = 0; r < 16; r++) {
                const int cr = (r & 3) + 8 * (r >> 2) + 4 * hi;
                if (kv0 + cr > q)      s0[r] = -3e38f;
                if (kv0 + 32 + cr > q) s1[r] = -3e38f;
            }
        }
        // fixed-m softmax with pre-scaled Q: P = exp2(S); masked -> 0
        float p0[16], p1[16];
#pragma unroll
        for (int r = 0; r < 16; r++) {
            p0[r] = exp2f(s0[r]);
            p1[r] = exp2f(s1[r]);
        }
#pragma unroll
        for (int g = 0; g < 2; g++) {
            u32 P2[8];
#pragma unroll
            for (int j = 0; j < 8; j++)
                P2[j] = g ? pk2(p1[2 * j], p1[2 * j + 1]) : pk2(p0[2 * j], p0[2 * j + 1]);
            auto s02 = __builtin_amdgcn_permlane32_swap((int)P2[0], (int)P2[2], false, false);
            auto s13 = __builtin_amdgcn_permlane32_swap((int)P2[1], (int)P2[3], false, false);
            auto s46 = __builtin_amdgcn_permlane32_swap((int)P2[4], (int)P2[6], false, false);
            auto s57 = __builtin_amdgcn_permlane32_swap((int)P2[5], (int)P2[7], false, false);
            v4i w0, w1;
            w0[0] = s02[0]; w0[1] = s13[0]; w0[2] = s02[1]; w0[3] = s13[1];
            w1[0] = s46[0]; w1[1] = s57[0]; w1[2] = s46[1]; w1[3] = s57[1];
            const bf16x8 pa0 = __builtin_bit_cast(bf16x8, w0);
            const bf16x8 pa1 = __builtin_bit_cast(bf16x8, w1);
            lsum = __builtin_amdgcn_mfma_f32_32x32x16_bf16(onesf, pa0, lsum, 0, 0, 0);
            lsum = __builtin_amdgcn_mfma_f32_32x32x16_bf16(onesf, pa1, lsum, 0, 0, 0);
#pragma unroll
            for (int ks = 0; ks < 2; ks++) {
                const bf16x8 pa = ks ? pa1 : pa0;
                const int cb = g * 32 + ks * 16 + hi * 8;
                bf16x8 vfa = *(const bf16x8*)&Vs[bi][la * 64 + (cb ^ swl)];
                bf16x8 vfb = *(const bf16x8*)&Vs[bi][(32 + la) * 64 + (cb ^ swl)];
                O0 = __builtin_amdgcn_mfma_f32_32x32x16_bf16(vfa, pa, O0, 0, 0, 0);
                O1 = __builtin_amdgcn_mfma_f32_32x32x16_bf16(vfb, pa, O1, 0, 0, 0);
            }
        }
    };

    STAGE(0, 0);
    for (int t = 0; t < ntile; t += 2) {
        __syncthreads();                       // drains vmcnt -> buf0 ready; buf1 readers done
        STAGE(1, (t + 1) * 64);                // prefetch flies under compute
        if (t <= lastt) COMPUTE(0, t);
        __syncthreads();                       // drains vmcnt -> buf1 ready; buf0 readers done
        if (t + 2 < ntile) STAGE(0, (t + 2) * 64);
        if (t + 1 <= lastt) COMPUTE(1, t + 1);
    }

    const float inv = 1.f / lsum[0];
    u16* yrow = Yb + ((size_t)(b * T_) + q) * C_ + h * HD_;
#pragma unroll
    for (int r4 = 0; r4 < 4; r4++) {
        u32x2 st0, st1;
        st0[0] = pk2(O0[r4 * 4 + 0] * inv, O0[r4 * 4 + 1] * inv);
        st0[1] = pk2(O0[r4 * 4 + 2] * inv, O0[r4 * 4 + 3] * inv);
        st1[0] = pk2(O1[r4 * 4 + 0] * inv, O1[r4 * 4 + 1] * inv);
        st1[1] = pk2(O1[r4 * 4 + 2] * inv, O1[r4 * 4 + 3] * inv);
        *(u32x2*)(yrow + r4 * 8 + hi * 4)      = st0;
        *(u32x2*)(yrow + 32 + r4 * 8 + hi * 4) = st1;
    }
}

extern "C" void kernel_launch(void* const* d_in, const int* in_sizes, int n_in,
                              void* d_out, int out_size, void* d_ws, size_t ws_size,
                              hipStream_t stream) {
    const float* x      = (const float*)d_in[0];
    const float* w_attn = (const float*)d_in[1];
    const float* w_proj = (const float*)d_in[2];
    float* out = (float*)d_out;
    char* ws = (char*)d_ws;
    // lifetime-overlapped workspace, peak ~104.3 MB
    u16* Wpb = (u16*)(ws + 0);              // 2 MB,   live: all
    u16* Rp  = (u16*)(ws + 2097152);        // 256 KB, live: -> norm
    u16* Xb  = (u16*)(ws + 2359296);        // 16 MB,  live: -> gemm1
    u16* Wab = (u16*)(ws + 19136512);       // 6 MB,   live: -> gemm1
    u16* QKV = (u16*)(ws + 25427968);       // 48 MB,  live: gemm1 -> norm
    u16* Qn  = (u16*)(ws + 2359296);        // 16 MB,  over Xb (dead), norm -> attn
    u16* Kn  = (u16*)(ws + 75759616);       // 16 MB,  norm -> attn
    u16* Vt  = (u16*)(ws + 92536832);       // 16 MB,  norm -> attn  [bh][d][t]
    u16* Yb  = (u16*)(ws + 25427968);       // 16 MB,  over QKV (dead), attn -> gemm2

    cast_f32_bf16<<<8192, 256, 0, stream>>>(x, Xb, 2097152);
    cast_f32_bf16<<<3072, 256, 0, stream>>>(w_attn, Wab, 786432);
    cast_f32_bf16<<<1024, 256, 0, stream>>>(w_proj, Wpb, 262144);
    rope_tab<<<256, 256, 0, stream>>>(Rp);
    gemm_bt5<u16><<<dim3(24, 64), 256, 0, stream>>>(Xb, Wab, QKV, 8192, 3072, 1024);
    norm_rope3<<<4096, 256, 0, stream>>>(QKV, Qn, Kn, Vt, Rp);
    attn_fwd9<<<1024, 256, 0, stream>>>(Qn, Kn, Vt, Yb);
    gemm_bt5<float><<<dim3(8, 64), 256, 0, stream>>>(Yb, Wpb, out, 8192, 1024, 1024);
}

// Round 14
// 187.187 us; speedup vs baseline: 1.4217x; 1.0016x over previous
//
#include <hip/hip_runtime.h>

typedef unsigned short u16;
typedef unsigned int u32;
typedef __attribute__((ext_vector_type(4))) int v4i;
typedef __attribute__((ext_vector_type(4))) float f32x4;
typedef __attribute__((ext_vector_type(16))) float f32x16;
typedef __attribute__((ext_vector_type(4))) u16 v4u;
typedef __attribute__((ext_vector_type(2))) u32 u32x2;
typedef __attribute__((ext_vector_type(8))) __bf16 bf16x8;

#define B_ 4
#define T_ 2048
#define C_ 1024
#define H_ 16
#define HD_ 64
#define C3_ 3072

__device__ __forceinline__ u16 f2b(float f) {
    unsigned u = __builtin_bit_cast(unsigned, f);
    u += 0x7FFFu + ((u >> 16) & 1u);
    return (u16)(u >> 16);
}
__device__ __forceinline__ float b2f(u16 h) {
    unsigned u = ((unsigned)h) << 16;
    return __builtin_bit_cast(float, u);
}
__device__ __forceinline__ u32 pk2(float lo, float hi) {
    __bf16 a = (__bf16)lo, b = (__bf16)hi;
    return (u32)__builtin_bit_cast(u16, a) | ((u32)__builtin_bit_cast(u16, b) << 16);
}
// async global->LDS, 16B per lane; LDS dest = uniform base + lane*16
__device__ __forceinline__ void glds16(const u16* g, u16* l) {
    __builtin_amdgcn_global_load_lds((const __attribute__((address_space(1))) void*)g,
                                     (__attribute__((address_space(3))) void*)l, 16, 0, 0);
}

// ---------------- cast f32 -> bf16 ----------------
__global__ __launch_bounds__(256) void cast_f32_bf16(const float* __restrict__ in,
                                                     u16* __restrict__ out, int n4) {
    int i = blockIdx.x * 256 + threadIdx.x;
    if (i >= n4) return;
    f32x4 v = *(const f32x4*)(in + (size_t)i * 4);
    v4u o;
    o[0] = f2b(v[0]); o[1] = f2b(v[1]); o[2] = f2b(v[2]); o[3] = f2b(v[3]);
    *(v4u*)(out + (size_t)i * 4) = o;
}

// ---------------- rope table ----------------
__global__ __launch_bounds__(256) void rope_tab(u16* __restrict__ rope) {
    int id = blockIdx.x * 256 + threadIdx.x;   // T_*32 entries
    int t = id >> 5, j = id & 31;
    float invf = exp2f(-(float)j * (13.287712379549449f / 32.0f));  // 10000^(-j/32)
    float fr = (float)t * invf;
    float s, c;
    sincosf(fr, &s, &c);
    rope[id * 2]     = f2b(c);
    rope[id * 2 + 1] = f2b(s);
}

// ---------------- GEMM v5: BK=64 glds + XOR swizzle + bijective XCD remap ----
__device__ __forceinline__ void store_out(u16* p, float v)   { *p = f2b(v); }
__device__ __forceinline__ void store_out(float* p, float v) { *p = v; }

template <typename OutT>
__global__ __launch_bounds__(256) void gemm_bt5(const u16* __restrict__ A, const u16* __restrict__ Bm,
                                                OutT* __restrict__ Cout, int Mdim, int Ndim, int Kdim) {
    __shared__ u16 As[8192];     // [128][64] swizzled, 16 KB
    __shared__ u16 Bs[8192];
    const int tid = threadIdx.x;
    // T1: bijective XCD remap (nwg % 8 == 0 for all our launches)
    const int F = blockIdx.y * gridDim.x + blockIdx.x;
    const int cpx = (gridDim.x * gridDim.y) >> 3;
    const int wg = (F & 7) * cpx + (F >> 3);
    const int row0 = (wg / gridDim.x) * 128;
    const int col0 = (wg % gridDim.x) * 128;
    const int w = tid >> 6, lane = tid & 63;
    const int wm = w >> 1, wn = w & 1;
    const int lr = lane & 15, lk = lane >> 4;

    const f32x4 zf = {0.f, 0.f, 0.f, 0.f};
    f32x4 acc[4][4];
#pragma unroll
    for (int m = 0; m < 4; m++)
#pragma unroll
        for (int n = 0; n < 4; n++) acc[m][n] = zf;

    const u16* Ab = A + (size_t)row0 * Kdim;
    const u16* Bb = Bm + (size_t)col0 * Kdim;
    const int srw = lane >> 3;                       // 0..7 within inst
    const int gch = (lane & 7) ^ (srw & 7);          // inverse swizzle on global source
    const size_t grow[4] = {
        (size_t)(w * 32 + 0 * 8 + srw) * Kdim + gch * 8,
        (size_t)(w * 32 + 1 * 8 + srw) * Kdim + gch * 8,
        (size_t)(w * 32 + 2 * 8 + srw) * Kdim + gch * 8,
        (size_t)(w * 32 + 3 * 8 + srw) * Kdim + gch * 8 };
    const int rx = lr & 7;

    for (int k0 = 0; k0 < Kdim; k0 += 64) {
#pragma unroll
        for (int j = 0; j < 4; j++) glds16(Ab + grow[j] + k0, As + (w * 32 + j * 8) * 64);
#pragma unroll
        for (int j = 0; j < 4; j++) glds16(Bb + grow[j] + k0, Bs + (w * 32 + j * 8) * 64);
        __syncthreads();
#pragma unroll
        for (int kk = 0; kk < 2; kk++) {
            const int chx = ((kk * 4 + lk) ^ rx) * 8;
            bf16x8 af[4], bfr[4];
#pragma unroll
            for (int m = 0; m < 4; m++) af[m]  = *(const bf16x8*)&As[(wm * 64 + m * 16 + lr) * 64 + chx];
#pragma unroll
            for (int n = 0; n < 4; n++) bfr[n] = *(const bf16x8*)&Bs[(wn * 64 + n * 16 + lr) * 64 + chx];
#pragma unroll
            for (int m = 0; m < 4; m++)
#pragma unroll
                for (int n = 0; n < 4; n++)
                    acc[m][n] = __builtin_amdgcn_mfma_f32_16x16x32_bf16(af[m], bfr[n], acc[m][n], 0, 0, 0);
        }
        __syncthreads();
    }
#pragma unroll
    for (int m = 0; m < 4; m++)
#pragma unroll
        for (int n = 0; n < 4; n++) {
            const int rr = row0 + wm * 64 + m * 16 + lk * 4;
            const int cc = col0 + wn * 64 + n * 16 + lr;
#pragma unroll
            for (int j = 0; j < 4; j++)
                store_out(Cout + (size_t)(rr + j) * Ndim + cc, acc[m][n][j]);
        }
}

// ---------------- RMSNorm + RoPE v3: LDS-free Q/K (16B stores), LDS V-transpose
__global__ __launch_bounds__(256) void norm_rope3(const u16* __restrict__ qkv, u16* __restrict__ Qn,
                                                  u16* __restrict__ Kn, u16* __restrict__ Vt,
                                                  const u16* __restrict__ rope) {
    __shared__ u16 sl[32][72];
    const int tid = threadIdx.x, bid = blockIdx.x;
    const int tt = bid & 63, bh = bid >> 6;
    const int b = bh >> 4, h = bh & 15;
    const int rl = tid >> 3, g = tid & 7;
    const int t = tt * 32 + rl;
    const size_t rowbase = ((size_t)(b * T_) + t) * C3_ + h * HD_;
    const size_t obase = ((size_t)bh * T_ + t) * HD_ + g * 8;
    *(v4i*)&sl[rl][g * 8] = *(const v4i*)(qkv + rowbase + 2 * C_ + g * 8);
    const u16* rp = rope + (size_t)t * 64;
#pragma unroll
    for (int p = 0; p < 2; p++) {            // p=0: q, p=1: k
        v4i rw = *(const v4i*)(qkv + rowbase + p * C_ + g * 8);
        float xv[8];
#pragma unroll
        for (int c = 0; c < 4; c++) {
            unsigned u = (unsigned)rw[c];
            xv[c * 2]     = b2f((u16)(u & 0xFFFFu));
            xv[c * 2 + 1] = b2f((u16)(u >> 16));
        }
        float ss = 0.f;
#pragma unroll
        for (int j = 0; j < 8; j++) ss += xv[j] * xv[j];
        ss += __shfl_xor(ss, 1, 64);
        ss += __shfl_xor(ss, 2, 64);
        ss += __shfl_xor(ss, 4, 64);
        const float rms = rsqrtf(ss * (1.f / 64.f) + 1.1920929e-7f);
        const float oscale = p == 0 ? 0.18033688011112042f : 1.0f;   // q: scale*log2(e)
#pragma unroll
        for (int j = 0; j < 8; j++) xv[j] *= rms;
        float xp[8];
#pragma unroll
        for (int j = 0; j < 8; j++) xp[j] = __shfl_xor(xv[j], 4, 64);
        float ys[8];
        if (g < 4) {
#pragma unroll
            for (int j = 0; j < 8; j++) {      // d = 8g+j < 32: y = x1*cos + x2*sin
                int d = g * 8 + j;
                ys[j] = xv[j] * b2f(rp[d * 2]) + xp[j] * b2f(rp[d * 2 + 1]);
            }
        } else {
#pragma unroll
            for (int j = 0; j < 8; j++) {      // dd = d-32: y = x2*cos - x1*sin
                int dd = (g - 4) * 8 + j;
                ys[j] = xv[j] * b2f(rp[dd * 2]) - xp[j] * b2f(rp[dd * 2 + 1]);
            }
        }
        v4i ov;
#pragma unroll
        for (int c = 0; c < 4; c++)
            ov[c] = (int)((unsigned)f2b(ys[c * 2] * oscale) | ((unsigned)f2b(ys[c * 2 + 1] * oscale) << 16));
        *(v4i*)((p ? Kn : Qn) + obase) = ov;
    }
    __syncthreads();
    const int d = tid >> 2, tq = tid & 3;
    v4i ov;
#pragma unroll
    for (int c = 0; c < 4; c++)
        ov[c] = (int)((unsigned)sl[tq * 8 + c * 2][d] | ((unsigned)sl[tq * 8 + c * 2 + 1][d] << 16));
    *(v4i*)(Vt + ((size_t)bh * HD_ + d) * T_ + tt * 32 + tq * 8) = ov;
}

// ---------------- causal flash attention v10: 8-wave blocks, balanced pairing
// Block = 512 thr = 8 waves x 32 q-rows = 256 q-rows; grid 512 = exactly 2/CU.
// Pairing map: r = gid>>6; qb = r<4 ? 7-r : r-4  -> any CU pair sums to 36 tiles.
// One K/V stage serves 8 waves (1 glds16/matrix/thread). T5 setprio in COMPUTE.
__global__ __launch_bounds__(512, 4) void attn_fwd10(const u16* __restrict__ Qn, const u16* __restrict__ Kn,
                                                     const u16* __restrict__ Vt, u16* __restrict__ Yb) {
    __shared__ u16 Ks[2][4096];
    __shared__ u16 Vs[2][4096];
    const int tid = threadIdx.x;
    const int w = tid >> 6, lane = tid & 63, la = lane & 31, hi = lane >> 5;
    const int gid = blockIdx.x;
    const int bh = gid & 63, r = gid >> 6;
    const int qb = (r < 4) ? (7 - r) : (r - 4);    // heavy half dispatched first
    const int b = bh >> 4, h = bh & 15;
    const int q0w = qb * 256 + w * 32;
    const int q = q0w + la;
    const u16* Qp = Qn + (size_t)bh * T_ * HD_;
    const u16* Kp = Kn + (size_t)bh * T_ * HD_;
    const u16* Vp = Vt + (size_t)bh * HD_ * T_;

    bf16x8 qf[4];
#pragma unroll
    for (int c = 0; c < 4; c++)
        qf[c] = *(const bf16x8*)(Qp + (size_t)q * HD_ + c * 16 + hi * 8);

    v4i oi; oi[0] = oi[1] = oi[2] = oi[3] = 0x3F803F80;        // bf16 1.0 x8
    const bf16x8 onesf = __builtin_bit_cast(bf16x8, oi);

    f32x16 O0, O1, lsum;
#pragma unroll
    for (int rr = 0; rr < 16; rr++) { O0[rr] = 0.f; O1[rr] = 0.f; lsum[rr] = 0.f; }
    const int lastt = q0w >> 6;
    const int ntile = 4 * qb + 4;              // always even
    // staging: wave w covers rows [w*8, w*8+8); 1 glds16 per matrix per thread
    const int s8 = lane >> 3;
    const int gch = (lane & 7) ^ s8;
    const int Rw = w * 8;
    const size_t kbase = (size_t)(Rw + s8) * HD_ + gch * 8;
    const size_t vbase = (size_t)(Rw + s8) * T_ + gch * 8;
    const int swl = (la & 7) << 3;                               // frag-read XOR

    auto STAGE = [&](int bi, int kv0) {
        glds16(Kp + kbase + (size_t)kv0 * HD_, &Ks[bi][Rw * 64]);
        glds16(Vp + vbase + kv0,               &Vs[bi][Rw * 64]);
    };
    auto COMPUTE = [&](int bi, int kt) {
        __builtin_amdgcn_s_setprio(1);
        const int kv0 = kt * 64;
        f32x16 s0, s1;
#pragma unroll
        for (int rr = 0; rr < 16; rr++) { s0[rr] = 0.f; s1[rr] = 0.f; }
#pragma unroll
        for (int c = 0; c < 4; c++) {
            const int cb = c * 16 + hi * 8;
            bf16x8 kfa = *(const bf16x8*)&Ks[bi][la * 64 + (cb ^ swl)];
            bf16x8 kfb = *(const bf16x8*)&Ks[bi][(32 + la) * 64 + (cb ^ swl)];
            s0 = __builtin_amdgcn_mfma_f32_32x32x16_bf16(kfa, qf[c], s0, 0, 0, 0);
            s1 = __builtin_amdgcn_mfma_f32_32x32x16_bf16(kfb, qf[c], s1, 0, 0, 0);
        }
        if (kt == lastt) {
#pragma unroll
            for (int rr = 0; rr < 16; rr++) {
                const int cr = (rr & 3) + 8 * (rr >> 2) + 4 * hi;
                if (kv0 + cr > q)      s0[rr] = -3e38f;
                if (kv0 + 32 + cr > q) s1[rr] = -3e38f;
            }
        }
        // fixed-m softmax with pre-scaled Q: P = exp2(S); masked -> 0
        float p0[16], p1[16];
#pragma unroll
        for (int rr = 0; rr < 16; rr++) {
            p0[rr] = exp2f(s0[rr]);
            p1[rr] = exp2f(s1[rr]);
        }
#pragma unroll
        for (int g = 0; g < 2; g++) {
            u32 P2[8];
#pragma unroll
            for (int j = 0; j < 8; j++)
                P2[j] = g ? pk2(p1[2 * j], p1[2 * j + 1]) : pk2(p0[2 * j], p0[2 * j + 1]);
            auto s02 = __builtin_amdgcn_permlane32_swap((int)P2[0], (int)P2[2], false, false);
            auto s13 = __builtin_amdgcn_permlane32_swap((int)P2[1], (int)P2[3], false, false);
            auto s46 = __builtin_amdgcn_permlane32_swap((int)P2[4], (int)P2[6], false, false);
            auto s57 = __builtin_amdgcn_permlane32_swap((int)P2[5], (int)P2[7], false, false);
            v4i w0, w1;
            w0[0] = s02[0]; w0[1] = s13[0]; w0[2] = s02[1]; w0[3] = s13[1];
            w1[0] = s46[0]; w1[1] = s57[0]; w1[2] = s46[1]; w1[3] = s57[1];
            const bf16x8 pa0 = __builtin_bit_cast(bf16x8, w0);
            const bf16x8 pa1 = __builtin_bit_cast(bf16x8, w1);
            lsum = __builtin_amdgcn_mfma_f32_32x32x16_bf16(onesf, pa0, lsum, 0, 0, 0);
            lsum = __builtin_amdgcn_mfma_f32_32x32x16_bf16(onesf, pa1, lsum, 0, 0, 0);
#pragma unroll
            for (int ks = 0; ks < 2; ks++) {
                const bf16x8 pa = ks ? pa1 : pa0;
                const int cb = g * 32 + ks * 16 + hi * 8;
                bf16x8 vfa = *(const bf16x8*)&Vs[bi][la * 64 + (cb ^ swl)];
                bf16x8 vfb = *(const bf16x8*)&Vs[bi][(32 + la) * 64 + (cb ^ swl)];
                O0 = __builtin_amdgcn_mfma_f32_32x32x16_bf16(vfa, pa, O0, 0, 0, 0);
                O1 = __builtin_amdgcn_mfma_f32_32x32x16_bf16(vfb, pa, O1, 0, 0, 0);
            }
        }
        __builtin_amdgcn_s_setprio(0);
    };

    STAGE(0, 0);
    for (int t = 0; t < ntile; t += 2) {
        __syncthreads();                       // drains vmcnt -> buf0 ready; buf1 readers done
        STAGE(1, (t + 1) * 64);                // prefetch flies under compute
        if (t <= lastt) COMPUTE(0, t);
        __syncthreads();                       // drains vmcnt -> buf1 ready; buf0 readers done
        if (t + 2 < ntile) STAGE(0, (t + 2) * 64);
        if (t + 1 <= lastt) COMPUTE(1, t + 1);
    }

    const float inv = 1.f / lsum[0];
    u16* yrow = Yb + ((size_t)(b * T_) + q) * C_ + h * HD_;
#pragma unroll
    for (int r4 = 0; r4 < 4; r4++) {
        u32x2 st0, st1;
        st0[0] = pk2(O0[r4 * 4 + 0] * inv, O0[r4 * 4 + 1] * inv);
        st0[1] = pk2(O0[r4 * 4 + 2] * inv, O0[r4 * 4 + 3] * inv);
        st1[0] = pk2(O1[r4 * 4 + 0] * inv, O1[r4 * 4 + 1] * inv);
        st1[1] = pk2(O1[r4 * 4 + 2] * inv, O1[r4 * 4 + 3] * inv);
        *(u32x2*)(yrow + r4 * 8 + hi * 4)      = st0;
        *(u32x2*)(yrow + 32 + r4 * 8 + hi * 4) = st1;
    }
}

extern "C" void kernel_launch(void* const* d_in, const int* in_sizes, int n_in,
                              void* d_out, int out_size, void* d_ws, size_t ws_size,
                              hipStream_t stream) {
    const float* x      = (const float*)d_in[0];
    const float* w_attn = (const float*)d_in[1];
    const float* w_proj = (const float*)d_in[2];
    float* out = (float*)d_out;
    char* ws = (char*)d_ws;
    // lifetime-overlapped workspace, peak ~104.3 MB
    u16* Wpb = (u16*)(ws + 0);              // 2 MB,   live: all
    u16* Rp  = (u16*)(ws + 2097152);        // 256 KB, live: -> norm
    u16* Xb  = (u16*)(ws + 2359296);        // 16 MB,  live: -> gemm1
    u16* Wab = (u16*)(ws + 19136512);       // 6 MB,   live: -> gemm1
    u16* QKV = (u16*)(ws + 25427968);       // 48 MB,  live: gemm1 -> norm
    u16* Qn  = (u16*)(ws + 2359296);        // 16 MB,  over Xb (dead), norm -> attn
    u16* Kn  = (u16*)(ws + 75759616);       // 16 MB,  norm -> attn
    u16* Vt  = (u16*)(ws + 92536832);       // 16 MB,  norm -> attn  [bh][d][t]
    u16* Yb  = (u16*)(ws + 25427968);       // 16 MB,  over QKV (dead), attn -> gemm2

    cast_f32_bf16<<<8192, 256, 0, stream>>>(x, Xb, 2097152);
    cast_f32_bf16<<<3072, 256, 0, stream>>>(w_attn, Wab, 786432);
    cast_f32_bf16<<<1024, 256, 0, stream>>>(w_proj, Wpb, 262144);
    rope_tab<<<256, 256, 0, stream>>>(Rp);
    gemm_bt5<u16><<<dim3(24, 64), 256, 0, stream>>>(Xb, Wab, QKV, 8192, 3072, 1024);
    norm_rope3<<<4096, 256, 0, stream>>>(QKV, Qn, Kn, Vt, Rp);
    attn_fwd10<<<512, 512, 0, stream>>>(Qn, Kn, Vt, Yb);
    gemm_bt5<float><<<dim3(8, 64), 256, 0, stream>>>(Yb, Wpb, out, 8192, 1024, 1024);
}